// Round 11
// baseline (777.429 us; speedup 1.0000x reference)
//
#include <hip/hip_runtime.h>
#include <hip/hip_bf16.h>
#include <string.h>

// Problem constants
#define N_POS 480000      // B*T*V = 64*300*25
#define NB    64
#define NT    300
#define NV    25
#define NCC   100
#define NTL   9
#define NL    292         // T - TL + 1

// Workspace float offsets. Atomic targets live on PRIVATE 64B cache lines
// (stride-16 floats) -- same-line atomic RMWs serialize at ~31cyc/op (R7).
#define WS_XA     0       // 9 accumulators at stride 16 (0,16,...,128)
#define WS_Z2SUM  144
#define WS_Z2SQ   160
#define WS_LOSS   176
#define WS_PAN    192
#define WS_REG    208
#define WS_SC1    224     // 128
#define WS_SH1    352     // 128
#define WS_SC2    480
#define WS_SH2    481
#define WS_WA     512     // 256: packed (sc*w0, sc*w1, sc*w2, ba) per ch
#define WS_W1T    768     // 8192: W1 transposed [c][o]
#define WS_SW     8960    // 2500 = sum_l weight^2 (100x25)
#define WS_HM     11460   // 1600 (B*V t-means)
#define WS_Z1P    13060   // 500*128 z1 sum partials; REUSED by k_mlp as 64
                          // loss-partial lines after k_z1red (re-zeroed)
#define WS_Z1PQ   77060   // 500*128 z1 sumsq partials
#define WS_Z2     141060  // 480000 (b,t,v)
#define WS_XS     621060  // 480000 (b,v,t)
#define WS_CM     1101060 // 4,000,000 (b,c,i,j)
#define WS_P      5101060 // fp32 p buffer starts here

__device__ __forceinline__ float waveRed(float v) {
    #pragma unroll
    for (int off = 32; off > 0; off >>= 1) v += __shfl_down(v, off);
    return v;
}

// ---------------- Pass A: x channel stats (float4, block-reduced) ----------
__global__ __launch_bounds__(256) void k_xstats(const float* __restrict__ x,
                                                float* __restrict__ ws) {
    __shared__ float s_red[4][9];
    int tid = blockIdx.x * 256 + threadIdx.x;
    int nth = gridDim.x * 256;
    float a[9];
    #pragma unroll
    for (int i = 0; i < 9; i++) a[i] = 0.f;
    for (int task = tid; task < 120000; task += nth) {
        int b = task / 1875; int q = task - b*1875;
        const float* xb = x + b*22500 + q*4;
        float4 v0 = *(const float4*)(xb);
        float4 v1 = *(const float4*)(xb + 7500);
        float4 v2 = *(const float4*)(xb + 15000);
        const float* p0 = (const float*)&v0;
        const float* p1 = (const float*)&v1;
        const float* p2 = (const float*)&v2;
        #pragma unroll
        for (int k = 0; k < 4; k++) {
            float x0 = p0[k], x1 = p1[k], x2 = p2[k];
            a[0] += x0; a[1] += x1; a[2] += x2;
            a[3] = fmaf(x0,x0,a[3]); a[4] = fmaf(x0,x1,a[4]); a[5] = fmaf(x0,x2,a[5]);
            a[6] = fmaf(x1,x1,a[6]); a[7] = fmaf(x1,x2,a[7]); a[8] = fmaf(x2,x2,a[8]);
        }
    }
    #pragma unroll
    for (int i = 0; i < 9; i++) a[i] = waveRed(a[i]);
    int w = threadIdx.x >> 6;
    if ((threadIdx.x & 63) == 0) {
        #pragma unroll
        for (int i = 0; i < 9; i++) s_red[w][i] = a[i];
    }
    __syncthreads();
    if (threadIdx.x < 9) {
        float s = s_red[0][threadIdx.x] + s_red[1][threadIdx.x]
                + s_red[2][threadIdx.x] + s_red[3][threadIdx.x];
        atomicAdd(&ws[WS_XA + threadIdx.x*16], s);
    }
}

// ---------------- sw[c,m] = sum_l weight^2 ----------------
__global__ void k_prepw(const float* __restrict__ weight, float* __restrict__ ws) {
    int idx = blockIdx.x * blockDim.x + threadIdx.x;
    if (idx < 2500) {
        float s = 0;
        #pragma unroll
        for (int l = 0; l < NTL; l++) { float w = weight[idx*NTL + l]; s += w*w; }
        ws[WS_SW + idx] = s;
    }
}

// ---------------- W1 transpose: W1T[c][o] = w1[o][c] ----------------
__global__ void k_prepw1t(const float* __restrict__ w1g, float* __restrict__ ws) {
    int idx = blockIdx.x * 256 + threadIdx.x;
    if (idx < 8192) {
        int c = idx >> 7, o = idx & 127;
        ws[WS_W1T + idx] = w1g[o*64 + c];
    }
}

// ---------------- BN0 folded affine from x moments (exact linearity) -------
__global__ void k_prep0(const float* __restrict__ w, const float* __restrict__ bb,
                        const float* __restrict__ g, const float* __restrict__ bt,
                        float* __restrict__ ws) {
    int o = threadIdx.x; // 64
    float inv = 1.0f / (float)N_POS;
    float mx0 = ws[WS_XA+0]*inv, mx1 = ws[WS_XA+16]*inv, mx2 = ws[WS_XA+32]*inv;
    float C00 = ws[WS_XA+48]*inv  - mx0*mx0;
    float C01 = ws[WS_XA+64]*inv  - mx0*mx1;
    float C02 = ws[WS_XA+80]*inv  - mx0*mx2;
    float C11 = ws[WS_XA+96]*inv  - mx1*mx1;
    float C12 = ws[WS_XA+112]*inv - mx1*mx2;
    float C22 = ws[WS_XA+128]*inv - mx2*mx2;
    float w0 = w[o*3], w1 = w[o*3+1], w2 = w[o*3+2];
    float mu  = w0*mx0 + w1*mx1 + w2*mx2 + bb[o];
    float var = w0*w0*C00 + w1*w1*C11 + w2*w2*C22
              + 2.f*(w0*w1*C01 + w0*w2*C02 + w1*w2*C12);
    float sc = g[o] / sqrtf(var + 1e-5f);
    float sh = bt[o] - sc*mu;
    ws[WS_WA + o*4 + 0] = sc*w0;
    ws[WS_WA + o*4 + 1] = sc*w1;
    ws[WS_WA + o*4 + 2] = sc*w2;
    ws[WS_WA + o*4 + 3] = sc*bb[o] + sh;
}

// ---------------- z1 GEMM pass (LDS-tiled, 4pos x 8out register tiles) ----
#define ZP_BLOCKS 500
#define ZP_CHUNKS 15
template<int MODE>
__global__ __launch_bounds__(256) void k_zpass(
        const float* __restrict__ x,
        const float* __restrict__ b1g,
        const float* __restrict__ w2g,
        const float* __restrict__ b2g,
        float* __restrict__ ws) {
    __shared__ float smem[12544];         // 50176 B
    float* s_h0  = smem;                  // [64 ch][68 pos-pad]
    float* s_w1t = smem + 4352;           // [64 c][128 o]
    int tid = threadIdx.x;

    for (int i = tid; i < 8192; i += 256) s_w1t[i] = ws[WS_W1T + i];

    int pos = tid & 63, cset = tid >> 6;  // staging mapping
    int pg  = tid >> 4, og  = tid & 15;   // GEMM mapping

    float b1r[8];
    #pragma unroll
    for (int o = 0; o < 8; o++) b1r[o] = b1g[og*8 + o];
    float sc1r[8], sh1r[8], w2r[8], b2v = 0.f;
    if constexpr (MODE == 1) {
        #pragma unroll
        for (int o = 0; o < 8; o++) {
            sc1r[o] = ws[WS_SC1 + og*8 + o];
            sh1r[o] = ws[WS_SH1 + og*8 + o];
            w2r[o]  = w2g[og*8 + o];
        }
        b2v = b2g[0];
    }
    float zs[8], zq[8];
    #pragma unroll
    for (int o = 0; o < 8; o++) { zs[o] = 0.f; zq[o] = 0.f; }
    float z2s = 0.f, z2q = 0.f;

    __syncthreads();

    for (int ci = 0; ci < ZP_CHUNKS; ci++) {
        int chunk = blockIdx.x * ZP_CHUNKS + ci;
        int P = chunk*64 + pos;
        int b = P / 7500, rem = P - b*7500;
        const float* xb = x + b*22500 + rem;
        float x0 = xb[0], x1 = xb[7500], x2 = xb[15000];
        #pragma unroll
        for (int k = 0; k < 16; k++) {
            int ch = cset*16 + k;
            const float4 wa = *(const float4*)&ws[WS_WA + ch*4];
            s_h0[ch*68 + pos] = fmaxf(wa.x*x0 + wa.y*x1 + wa.z*x2 + wa.w, 0.f);
        }
        __syncthreads();

        float acc[4][8];
        #pragma unroll
        for (int p = 0; p < 4; p++)
            #pragma unroll
            for (int o = 0; o < 8; o++) acc[p][o] = 0.f;

        #pragma unroll 4
        for (int c = 0; c < 64; c++) {
            float4 ha = *(const float4*)&s_h0[c*68 + 4*pg];
            float4 wl = *(const float4*)&s_w1t[c*128 + 8*og];
            float4 wh = *(const float4*)&s_w1t[c*128 + 8*og + 4];
            #pragma unroll
            for (int p = 0; p < 4; p++) {
                float hv = ((const float*)&ha)[p];
                #pragma unroll
                for (int o = 0; o < 4; o++) {
                    acc[p][o]   = fmaf(hv, ((const float*)&wl)[o], acc[p][o]);
                    acc[p][o+4] = fmaf(hv, ((const float*)&wh)[o], acc[p][o+4]);
                }
            }
        }

        if constexpr (MODE == 0) {
            #pragma unroll
            for (int o = 0; o < 8; o++) {
                #pragma unroll
                for (int p = 0; p < 4; p++) {
                    float z = acc[p][o] + b1r[o];
                    zs[o] += z; zq[o] += z*z;
                }
            }
            __syncthreads();   // protect s_h0 before next staging
        } else {
            float zp[4];
            #pragma unroll
            for (int p = 0; p < 4; p++) {
                float s = 0.f;
                #pragma unroll
                for (int o = 0; o < 8; o++) {
                    float z = acc[p][o] + b1r[o];
                    s += w2r[o]*fmaxf(sc1r[o]*z + sh1r[o], 0.f);
                }
                zp[p] = s;
            }
            __syncthreads();               // all GEMM reads of s_h0 done
            float* s_z2p = smem;           // [64 pos][17]
            #pragma unroll
            for (int p = 0; p < 4; p++) s_z2p[(4*pg + p)*17 + og] = zp[p];
            __syncthreads();
            if (tid < 64) {
                float z2 = b2v;
                #pragma unroll
                for (int j = 0; j < 16; j++) z2 += s_z2p[tid*17 + j];
                ws[WS_Z2 + chunk*64 + tid] = z2;
                z2s += z2; z2q += z2*z2;
            }
            __syncthreads();               // protect overlay before next staging
        }
    }

    if constexpr (MODE == 0) {
        // block partials -> global arrays (NO atomics; reduced by k_z1red)
        float* s_part = smem;              // [128 o][17]
        #pragma unroll
        for (int o = 0; o < 8; o++) s_part[(og*8 + o)*17 + pg] = zs[o];
        __syncthreads();
        if (tid < 128) {
            float s = 0.f;
            #pragma unroll
            for (int j = 0; j < 16; j++) s += s_part[tid*17 + j];
            ws[WS_Z1P + blockIdx.x*128 + tid] = s;
        }
        __syncthreads();
        #pragma unroll
        for (int o = 0; o < 8; o++) s_part[(og*8 + o)*17 + pg] = zq[o];
        __syncthreads();
        if (tid < 128) {
            float s = 0.f;
            #pragma unroll
            for (int j = 0; j < 16; j++) s += s_part[tid*17 + j];
            ws[WS_Z1PQ + blockIdx.x*128 + tid] = s;
        }
    } else {
        if (tid < 64) {
            z2s = waveRed(z2s);
            z2q = waveRed(z2q);
            if (tid == 0) { atomicAdd(&ws[WS_Z2SUM], z2s); atomicAdd(&ws[WS_Z2SQ], z2q); }
        }
    }
}

// ---------------- reduce z1 partials -> BN1 affine ----------
__global__ __launch_bounds__(256) void k_z1red(const float* __restrict__ g,
                                               const float* __restrict__ bt,
                                               float* __restrict__ ws) {
    __shared__ float ss[4], qq[4];
    int o = blockIdx.x;  // 0..127
    float s = 0.f, q = 0.f;
    for (int blk = threadIdx.x; blk < ZP_BLOCKS; blk += 256) {
        s += ws[WS_Z1P  + blk*128 + o];
        q += ws[WS_Z1PQ + blk*128 + o];
    }
    s = waveRed(s); q = waveRed(q);
    int w = threadIdx.x >> 6;
    if ((threadIdx.x & 63) == 0) { ss[w] = s; qq[w] = q; }
    __syncthreads();
    if (threadIdx.x == 0) {
        float S = ss[0]+ss[1]+ss[2]+ss[3];
        float Q = qq[0]+qq[1]+qq[2]+qq[3];
        float inv = 1.0f / (float)N_POS;
        float m = S*inv;
        float v = Q*inv - m*m;
        float sc = g[o] / sqrtf(v + 1e-5f);
        ws[WS_SC1+o] = sc;
        ws[WS_SH1+o] = bt[o] - sc*m;
    }
}

__global__ void k_prep2(const float* __restrict__ g, const float* __restrict__ bt,
                        float* __restrict__ ws) {
    float inv = 1.0f / (float)N_POS;
    float m = ws[WS_Z2SUM]*inv;
    float v = ws[WS_Z2SQ]*inv - m*m;
    float sc = g[0] / sqrtf(v + 1e-5f);
    ws[WS_SC2] = sc;
    ws[WS_SH2] = bt[0] - sc*m;
}

// ---------------- x_series (b,v,t) + per-(b,v) t-mean ----------------
__global__ void k_xs(float* __restrict__ ws) {
    __shared__ float red[128];
    int bid = blockIdx.x;       // b*25+v
    int b = bid / 25, v = bid - b*25;
    float sc = ws[WS_SC2], sh = ws[WS_SH2];
    float local = 0.f;
    for (int t = threadIdx.x; t < NT; t += 128) {
        float val = fmaxf(sc * ws[WS_Z2 + b*7500 + t*25 + v] + sh, 0.f);
        ws[WS_XS + (size_t)bid*NT + t] = val;
        local += val;
    }
    red[threadIdx.x] = local;
    __syncthreads();
    for (int s = 64; s > 0; s >>= 1) {
        if (threadIdx.x < s) red[threadIdx.x] += red[threadIdx.x + s];
        __syncthreads();
    }
    if (threadIdx.x == 0) ws[WS_HM + bid] = red[0] * (1.f/300.f);
}

// ---------------- cm[b,c,i,j] = tanh(x1[b,c,i]-x2[b,c,j]) ----------------
__global__ void k_cm(const float* __restrict__ c1w, const float* __restrict__ c1b,
                     const float* __restrict__ c2w, const float* __restrict__ c2b,
                     float* __restrict__ ws) {
    __shared__ float s_hm[25];
    int bid = blockIdx.x;       // b*100+c
    int b = bid / 100, c = bid - b*100;
    if (threadIdx.x < 25) s_hm[threadIdx.x] = ws[WS_HM + b*25 + threadIdx.x];
    float a1 = c1w[c], d1 = c1b[c], a2 = c2w[c], d2 = c2b[c];
    __syncthreads();
    for (int idx = threadIdx.x; idx < 625; idx += 256) {
        int i = idx / 25, j = idx - i*25;
        ws[WS_CM + (size_t)bid*625 + idx] = tanhf(a1*s_hm[i] + d1 - a2*s_hm[j] - d2);
    }
}

// ---------------- GCs ----------------
__global__ void k_gcs(const float* __restrict__ ws, float* __restrict__ out) {
    int gid = blockIdx.x * 256 + threadIdx.x;
    if (gid < 40000) {
        int b = gid / 625; int rem = gid - b*625; int m = rem % 25;
        float acc = 0.f;
        for (int c = 0; c < 100; c++) {
            float v = ws[WS_CM + ((size_t)(b*100+c))*625 + rem];
            acc += v*v*ws[WS_SW + c*25 + m];
        }
        out[gid] = sqrtf(acc);
    }
}

// ---------------- panelty ----------------
__global__ void k_pan(float* __restrict__ ws) {
    __shared__ float s_colsq[25];
    __shared__ float s_n1, s_r;
    int tid = threadIdx.x;
    int b = blockIdx.x;
    if (tid < 25) s_colsq[tid] = 0.f;
    if (tid == 0) { s_n1 = 0.f; s_r = 0.f; }
    __syncthreads();
    float ln1 = 0.f;
    for (int idx = tid; idx < 625; idx += 256) {
        int j = idx % 25;
        float sq = 0.f;
        for (int c = 0; c < 100; c++) {
            float v = ws[WS_CM + ((size_t)(b*100+c))*625 + idx];
            sq += v*v;
        }
        ln1 += sqrtf(sq);
        atomicAdd(&s_colsq[j], sq);
    }
    ln1 = waveRed(ln1);
    if ((tid & 63) == 0) atomicAdd(&s_n1, ln1);
    __syncthreads();
    if (tid < 25) atomicAdd(&s_r, sqrtf(s_colsq[tid]));
    __syncthreads();
    if (tid == 0) atomicAdd(&ws[WS_PAN], s_n1 + s_r);
}

// ---------------- regularize ----------------
__global__ void k_reg(const float* __restrict__ f0w, const float* __restrict__ f1w,
                      const float* __restrict__ f2w, float* __restrict__ ws) {
    __shared__ float sred[4];
    int tid = blockIdx.x * blockDim.x + threadIdx.x;
    int nth = gridDim.x * blockDim.x;
    float a = 0.f;
    for (int i = tid; i < 275250; i += nth) {
        float w;
        if (i < 250000) w = f0w[i];
        else if (i < 275000) w = f1w[i - 250000];
        else w = f2w[i - 275000];
        a += w*w;
    }
    a = waveRed(a);
    int w = threadIdx.x >> 6;
    if ((threadIdx.x & 63) == 0) sred[w] = a;
    __syncthreads();
    if (threadIdx.x == 0)
        atomicAdd(&ws[WS_REG], sred[0]+sred[1]+sred[2]+sred[3]);
}

// ---------------- Fc + p per (b,c), register-tiled, t-split halves ----------
#define XP 156   // xs row pad
#define FP 152   // fc row pad
__global__ __launch_bounds__(256) void k_fcp(
        const float* __restrict__ weight, const float* __restrict__ wnorm,
        float* __restrict__ pbuf, const float* __restrict__ ws, int b_base) {
    __shared__ float s_xs[25*XP];   // 3900
    __shared__ float s_fc[25*FP];   // 3800
    __shared__ float s_wn[225];
    __shared__ float s_cm[625];
    int tid = threadIdx.x;
    int bid = blockIdx.x;
    int bl = bid / 100, c = bid - bl*100;
    int b = b_base + bl;

    for (int i = tid; i < 225; i += 256) s_wn[i] = weight[c*225 + i] / wnorm[i];
    for (int i = tid; i < 625; i += 256) s_cm[i] = ws[WS_CM + ((size_t)(b*100+c))*625 + i];

    #pragma unroll
    for (int h = 0; h < 2; h++) {
        const int t_base = h ? 148 : 0;
        const int TH     = h ? 144 : 148;
        const int NTQ4   = TH / 4;
        const int NPV    = ((TH + 7) / 8);

        for (int i = tid; i < 25*XP; i += 256) {
            int v = i / XP, u = i - v*XP;
            if (u < TH + 8) s_xs[i] = ws[WS_XS + (size_t)(b*25+v)*NT + t_base + u];
        }
        __syncthreads();

        for (int task = tid; task < 25*NTQ4; task += 256) {
            int v = task / NTQ4, tq = task - v*NTQ4;
            int t0 = tq*4;
            float4 xa = *(const float4*)&s_xs[v*XP + t0];
            float4 xb = *(const float4*)&s_xs[v*XP + t0 + 4];
            float4 xc = *(const float4*)&s_xs[v*XP + t0 + 8];
            float xr[12];
            xr[0]=xa.x; xr[1]=xa.y; xr[2]=xa.z; xr[3]=xa.w;
            xr[4]=xb.x; xr[5]=xb.y; xr[6]=xb.z; xr[7]=xb.w;
            xr[8]=xc.x; xr[9]=xc.y; xr[10]=xc.z; xr[11]=xc.w;
            float f[4];
            #pragma unroll
            for (int k = 0; k < 4; k++) f[k] = 0.f;
            #pragma unroll
            for (int l = 0; l < NTL; l++) {
                float w = s_wn[v*NTL + l];
                #pragma unroll
                for (int k = 0; k < 4; k++) f[k] = fmaf(xr[k + l], w, f[k]);
            }
            *(float4*)&s_fc[v*FP + t0] = make_float4(f[0], f[1], f[2], f[3]);
        }
        __syncthreads();

        for (int task = tid; task < NPV*25; task += 256) {
            int tq = task / 25, ii = task - tq*25;
            int t0 = tq*8;
            float cmv[25];
            #pragma unroll
            for (int v = 0; v < 25; v++) cmv[v] = s_cm[v*25 + ii];
            float acc[8];
            #pragma unroll
            for (int k = 0; k < 8; k++) acc[k] = 0.f;
            #pragma unroll
            for (int v = 0; v < 25; v++) {
                float4 f0 = *(const float4*)&s_fc[v*FP + t0];
                float4 f1 = *(const float4*)&s_fc[v*FP + t0 + 4];
                float cv = cmv[v];
                acc[0] = fmaf(cv, f0.x, acc[0]);
                acc[1] = fmaf(cv, f0.y, acc[1]);
                acc[2] = fmaf(cv, f0.z, acc[2]);
                acc[3] = fmaf(cv, f0.w, acc[3]);
                acc[4] = fmaf(cv, f1.x, acc[4]);
                acc[5] = fmaf(cv, f1.y, acc[5]);
                acc[6] = fmaf(cv, f1.z, acc[6]);
                acc[7] = fmaf(cv, f1.w, acc[7]);
            }
            size_t row = (size_t)((bl*25 + ii)*100 + c);
            size_t gbase = row*NL + t_base + t0;
            *(float4*)(pbuf + gbase) = make_float4(acc[0], acc[1], acc[2], acc[3]);
            if (t0 + 8 <= TH)
                *(float4*)(pbuf + gbase + 4) = make_float4(acc[4], acc[5], acc[6], acc[7]);
        }
        __syncthreads();
    }
}

// ---------------- group MLP: LDS-tiled GEMM (R10 rewrite) ------------------
// block = (bl, g, t-chunk of 64); grid = nb*125. C[o][t] = relu(W0 P + b0),
// o padded to 128. Thread (pg,og) owns 4t x 8o. Layer1 via 16-lane butterfly.
__global__ __launch_bounds__(256) void k_mlp(
        const float* __restrict__ pbuf,
        const float* __restrict__ f0w, const float* __restrict__ f0b,
        const float* __restrict__ f1w, const float* __restrict__ f1b,
        const float* __restrict__ f2w, const float* __restrict__ f2b,
        float* __restrict__ ws, int b_base) {
    __shared__ float sm[11680];      // sP [52][68] | sW [52][132] | sW1 [10][128]
    __shared__ float s_loss;
    float* sP  = sm;
    float* sW  = sm + 3536;
    float* sW1 = sm + 10400;
    int tid = threadIdx.x;
    int bid = blockIdx.x;
    int bl = bid / 125; int rem = bid - bl*125;
    int g = rem / 5;    int tc = rem - g*5;
    int t0 = tc*64;
    int b = b_base + bl;
    int og = tid & 15, pg = tid >> 4;

    // stage w1T [o2][128], zero-pad o>=100
    for (int i = tid; i < 1280; i += 256) {
        int o2 = i >> 7, o = i & 127;
        sW1[i] = (o < 100) ? f1w[g*1000 + o2*100 + o] : 0.f;
    }
    if (tid == 0) s_loss = 0.f;

    const float* Pbase = pbuf + (size_t)(bl*25 + g)*100*NL;
    const float* W0 = f0w + g*10000;

    float acc[4][8];
    #pragma unroll
    for (int p = 0; p < 4; p++)
        #pragma unroll
        for (int k = 0; k < 8; k++) acc[p][k] = 0.f;

    #pragma unroll
    for (int ch = 0; ch < 2; ch++) {
        const int c0 = ch ? 52 : 0;
        const int KL = ch ? 48 : 52;
        const int NQ = KL / 4;          // 13 / 12
        if (ch) __syncthreads();        // GEMM-a reads done before restage
        // stage P chunk [KL][68]; zero t>=292
        for (int i = tid; i < KL*16; i += 256) {
            int r = i >> 4, q = i & 15;
            int t = t0 + 4*q;
            float4 v = make_float4(0.f, 0.f, 0.f, 0.f);
            if (t < NL) v = *(const float4*)(Pbase + (size_t)(c0 + r)*NL + t);
            *(float4*)&sP[r*68 + 4*q] = v;
        }
        // stage W0T chunk [KL][132]: cols 0..99 from W0, 100..127 zero
        for (int i = tid; i < 100*NQ; i += 256) {
            int o = i / NQ, q = i - o*NQ;
            float4 v = *(const float4*)(W0 + o*100 + c0 + 4*q);
            sW[(4*q+0)*132 + o] = v.x;
            sW[(4*q+1)*132 + o] = v.y;
            sW[(4*q+2)*132 + o] = v.z;
            sW[(4*q+3)*132 + o] = v.w;
        }
        for (int i = tid; i < KL*28; i += 256) {
            int r = i / 28, o = 100 + (i - r*28);
            sW[r*132 + o] = 0.f;
        }
        __syncthreads();
        #pragma unroll 4
        for (int c = 0; c < KL; c++) {
            float4 pv = *(const float4*)&sP[c*68 + 4*pg];
            float4 wl = *(const float4*)&sW[c*132 + 8*og];
            float4 wh = *(const float4*)&sW[c*132 + 8*og + 4];
            #pragma unroll
            for (int p = 0; p < 4; p++) {
                float hv = ((const float*)&pv)[p];
                #pragma unroll
                for (int k = 0; k < 4; k++) {
                    acc[p][k]   = fmaf(hv, ((const float*)&wl)[k], acc[p][k]);
                    acc[p][k+4] = fmaf(hv, ((const float*)&wh)[k], acc[p][k+4]);
                }
            }
        }
    }

    // h1 = relu(acc + b0) in place
    float b0r[8];
    #pragma unroll
    for (int k = 0; k < 8; k++) {
        int o = og*8 + k;
        b0r[k] = (o < 100) ? f0b[g*100 + o] : 0.f;
    }
    #pragma unroll
    for (int p = 0; p < 4; p++)
        #pragma unroll
        for (int k = 0; k < 8; k++)
            acc[p][k] = fmaxf(acc[p][k] + b0r[k], 0.f);

    // layer-1 partials + 16-lane butterfly over og
    float acc2[4][10];
    #pragma unroll
    for (int o2 = 0; o2 < 10; o2++) {
        float4 wA = *(const float4*)&sW1[o2*128 + og*8];
        float4 wB = *(const float4*)&sW1[o2*128 + og*8 + 4];
        #pragma unroll
        for (int p = 0; p < 4; p++) {
            float s;
            s  = wA.x*acc[p][0]; s = fmaf(wA.y, acc[p][1], s);
            s = fmaf(wA.z, acc[p][2], s); s = fmaf(wA.w, acc[p][3], s);
            s = fmaf(wB.x, acc[p][4], s); s = fmaf(wB.y, acc[p][5], s);
            s = fmaf(wB.z, acc[p][6], s); s = fmaf(wB.w, acc[p][7], s);
            acc2[p][o2] = s;
        }
    }
    #pragma unroll
    for (int m = 1; m < 16; m <<= 1)
        #pragma unroll
        for (int p = 0; p < 4; p++)
            #pragma unroll
            for (int o2 = 0; o2 < 10; o2++)
                acc2[p][o2] += __shfl_xor(acc2[p][o2], m);

    // layer-2 + loss (og==0 lanes; all og hold identical sums)
    float b1r[10], w2r[10];
    #pragma unroll
    for (int o2 = 0; o2 < 10; o2++) { b1r[o2] = f1b[g*10 + o2]; w2r[o2] = f2w[g*10 + o2]; }
    float b2 = f2b[g];
    float local = 0.f;
    if (og == 0) {
        #pragma unroll
        for (int p = 0; p < 4; p++) {
            int tg = t0 + 4*pg + p;
            float z3 = b2;
            #pragma unroll
            for (int o2 = 0; o2 < 10; o2++)
                z3 = fmaf(w2r[o2], fmaxf(acc2[p][o2] + b1r[o2], 0.f), z3);
            z3 = fmaxf(z3, 0.f);
            if (tg < NL-1) {
                float d = ws[WS_XS + (size_t)(b*25 + g)*NT + tg + NTL] - z3;
                local = fmaf(d, d, local);
            }
        }
    }
    local = waveRed(local);
    if ((tid & 63) == 0) atomicAdd(&s_loss, local);
    __syncthreads();
    if (tid == 0) atomicAdd(&ws[WS_Z1P + (bid & 63)*16], s_loss);
}

// ---------------- final scalars (reduce 64 loss partial lines) -------------
__global__ void k_final(float* __restrict__ out, const float* __restrict__ ws) {
    float v = ws[WS_Z1P + threadIdx.x*16];   // 64 threads
    v = waveRed(v);
    if (threadIdx.x == 0) out[40000] = v * (1.f / 465600.f);
    if (threadIdx.x == 1) out[40001] = 1e-4f * ws[WS_PAN];
    if (threadIdx.x == 2) out[40002] = 1e-4f * ws[WS_REG];
}

extern "C" void kernel_launch(void* const* d_in, const int* in_sizes, int n_in,
                              void* d_out, int out_size, void* d_ws, size_t ws_size,
                              hipStream_t stream) {
    const float* x      = (const float*)d_in[0];
    const float* weight = (const float*)d_in[1];
    const float* wnorm  = (const float*)d_in[2];
    const float* fb0_w  = (const float*)d_in[3];
    const float* fb0_b  = (const float*)d_in[4];
    const float* bn0_g  = (const float*)d_in[5];
    const float* bn0_b  = (const float*)d_in[6];
    const float* fb1_w  = (const float*)d_in[7];
    const float* fb1_b  = (const float*)d_in[8];
    const float* bn1_g  = (const float*)d_in[9];
    const float* bn1_b  = (const float*)d_in[10];
    const float* fb2_w  = (const float*)d_in[11];
    const float* fb2_b  = (const float*)d_in[12];
    const float* bn2_g  = (const float*)d_in[13];
    const float* bn2_b  = (const float*)d_in[14];
    const float* c1_w   = (const float*)d_in[15];
    const float* c1_b   = (const float*)d_in[16];
    const float* c2_w   = (const float*)d_in[17];
    const float* c2_b   = (const float*)d_in[18];
    const float* f0_w   = (const float*)d_in[19];
    const float* f0_b   = (const float*)d_in[20];
    const float* f1_w   = (const float*)d_in[21];
    const float* f1_b   = (const float*)d_in[22];
    const float* f2_w   = (const float*)d_in[23];
    const float* f2_b   = (const float*)d_in[24];

    float* ws  = (float*)d_ws;
    float* out = (float*)d_out;
    float* pbuf = ws + WS_P;

    // zero accumulators (floats 0..255; covers XA + scalar lines)
    hipMemsetAsync(d_ws, 0, 1024, stream);

    k_xstats<<<128, 256, 0, stream>>>(x, ws);
    k_prepw<<<10, 256, 0, stream>>>(weight, ws);
    k_prepw1t<<<32, 256, 0, stream>>>(fb1_w, ws);
    k_prep0<<<1, 64, 0, stream>>>(fb0_w, fb0_b, bn0_g, bn0_b, ws);
    k_zpass<0><<<ZP_BLOCKS, 256, 0, stream>>>(x, fb1_b, fb2_w, fb2_b, ws);
    k_z1red<<<128, 256, 0, stream>>>(bn1_g, bn1_b, ws);
    // Z1P region consumed by k_z1red; re-zero 64 lines for k_mlp loss partials
    hipMemsetAsync((char*)d_ws + (size_t)WS_Z1P*4, 0, 64*16*4, stream);
    k_zpass<1><<<ZP_BLOCKS, 256, 0, stream>>>(x, fb1_b, fb2_w, fb2_b, ws);
    k_prep2<<<1, 1, 0, stream>>>(bn2_g, bn2_b, ws);
    k_xs<<<1600, 128, 0, stream>>>(ws);
    k_cm<<<6400, 256, 0, stream>>>(c1_w, c1_b, c2_w, c2_b, ws);
    k_gcs<<<157, 256, 0, stream>>>(ws, out);
    k_pan<<<64, 256, 0, stream>>>(ws);
    k_reg<<<256, 256, 0, stream>>>(f0_w, f1_w, f2_w, ws);

    // Adaptive b-chunking for the fp32 p buffer
    const size_t p_bytes_per_b = (size_t)25*100*NL*sizeof(float); // 2.92 MB
    size_t fixed_bytes = (size_t)WS_P * sizeof(float);
    size_t avail = ws_size > fixed_bytes ? ws_size - fixed_bytes : 0;
    int bs = (int)(avail / p_bytes_per_b);
    if (bs > 64) bs = 64;
    if (bs < 1)  bs = 1;
    for (int b0 = 0; b0 < 64; b0 += bs) {
        int nb = (64 - b0) < bs ? (64 - b0) : bs;
        k_fcp<<<nb*100, 256, 0, stream>>>(weight, wnorm, pbuf, ws, b0);
        k_mlp<<<nb*125, 256, 0, stream>>>(pbuf, f0_w, f0_b, f1_w, f1_b,
                                          f2_w, f2_b, ws, b0);
    }
    k_final<<<1, 64, 0, stream>>>(out, ws);
}

// Round 12
// 733.322 us; speedup vs baseline: 1.0601x; 1.0601x over previous
//
#include <hip/hip_runtime.h>
#include <hip/hip_bf16.h>
#include <string.h>

// Problem constants
#define N_POS 480000      // B*T*V = 64*300*25
#define NB    64
#define NT    300
#define NV    25
#define NCC   100
#define NTL   9
#define NL    292         // T - TL + 1

// Workspace float offsets. Atomic targets live on PRIVATE 64B cache lines
// (stride-16 floats) -- same-line atomic RMWs serialize at ~31cyc/op (R7).
#define WS_XA     0       // 9 accumulators at stride 16 (0,16,...,128)
#define WS_Z2SUM  144
#define WS_Z2SQ   160
#define WS_LOSS   176
#define WS_PAN    192
#define WS_REG    208
#define WS_SC1    224     // 128
#define WS_SH1    352     // 128
#define WS_SC2    480
#define WS_SH2    481
#define WS_WA     512     // 256: packed (sc*w0, sc*w1, sc*w2, ba) per ch
#define WS_W1T    768     // 8192: W1 transposed [c][o]
#define WS_SW     8960    // 2500 = sum_l weight^2 (100x25)
#define WS_HM     11460   // 1600 (B*V t-means)
#define WS_Z1P    13060   // 500*128 z1 sum partials; REUSED by k_mlp as 64
                          // loss-partial lines after k_z1red (re-zeroed)
#define WS_Z1PQ   77060   // 500*128 z1 sumsq partials
#define WS_Z2     141060  // 480000 (b,t,v)
#define WS_XS     621060  // 480000 (b,v,t)
#define WS_CM     1101060 // 4,000,000 (b,c,i,j)
#define WS_P      5101060 // [W0T: 250000 floats][fp32 p buffer]

__device__ __forceinline__ float waveRed(float v) {
    #pragma unroll
    for (int off = 32; off > 0; off >>= 1) v += __shfl_down(v, off);
    return v;
}

// ---------------- Pass A: x channel stats (float4, block-reduced) ----------
__global__ __launch_bounds__(256) void k_xstats(const float* __restrict__ x,
                                                float* __restrict__ ws) {
    __shared__ float s_red[4][9];
    int tid = blockIdx.x * 256 + threadIdx.x;
    int nth = gridDim.x * 256;
    float a[9];
    #pragma unroll
    for (int i = 0; i < 9; i++) a[i] = 0.f;
    for (int task = tid; task < 120000; task += nth) {
        int b = task / 1875; int q = task - b*1875;
        const float* xb = x + b*22500 + q*4;
        float4 v0 = *(const float4*)(xb);
        float4 v1 = *(const float4*)(xb + 7500);
        float4 v2 = *(const float4*)(xb + 15000);
        const float* p0 = (const float*)&v0;
        const float* p1 = (const float*)&v1;
        const float* p2 = (const float*)&v2;
        #pragma unroll
        for (int k = 0; k < 4; k++) {
            float x0 = p0[k], x1 = p1[k], x2 = p2[k];
            a[0] += x0; a[1] += x1; a[2] += x2;
            a[3] = fmaf(x0,x0,a[3]); a[4] = fmaf(x0,x1,a[4]); a[5] = fmaf(x0,x2,a[5]);
            a[6] = fmaf(x1,x1,a[6]); a[7] = fmaf(x1,x2,a[7]); a[8] = fmaf(x2,x2,a[8]);
        }
    }
    #pragma unroll
    for (int i = 0; i < 9; i++) a[i] = waveRed(a[i]);
    int w = threadIdx.x >> 6;
    if ((threadIdx.x & 63) == 0) {
        #pragma unroll
        for (int i = 0; i < 9; i++) s_red[w][i] = a[i];
    }
    __syncthreads();
    if (threadIdx.x < 9) {
        float s = s_red[0][threadIdx.x] + s_red[1][threadIdx.x]
                + s_red[2][threadIdx.x] + s_red[3][threadIdx.x];
        atomicAdd(&ws[WS_XA + threadIdx.x*16], s);
    }
}

// ---------------- sw[c,m] = sum_l weight^2 ----------------
__global__ void k_prepw(const float* __restrict__ weight, float* __restrict__ ws) {
    int idx = blockIdx.x * blockDim.x + threadIdx.x;
    if (idx < 2500) {
        float s = 0;
        #pragma unroll
        for (int l = 0; l < NTL; l++) { float w = weight[idx*NTL + l]; s += w*w; }
        ws[WS_SW + idx] = s;
    }
}

// ---------------- W1 transpose: W1T[c][o] = w1[o][c] ----------------
__global__ void k_prepw1t(const float* __restrict__ w1g, float* __restrict__ ws) {
    int idx = blockIdx.x * 256 + threadIdx.x;
    if (idx < 8192) {
        int c = idx >> 7, o = idx & 127;
        ws[WS_W1T + idx] = w1g[o*64 + c];
    }
}

// ---------------- W0 transpose per group: W0T[g][c][o] = f0w[g][o][c] ------
__global__ void k_prepw0t(const float* __restrict__ f0w, float* __restrict__ w0t) {
    int idx = blockIdx.x * 256 + threadIdx.x;
    if (idx < 250000) {
        int g = idx / 10000; int r = idx - g*10000;
        int c = r / 100, o = r - c*100;
        w0t[idx] = f0w[g*10000 + o*100 + c];
    }
}

// ---------------- BN0 folded affine from x moments (exact linearity) -------
__global__ void k_prep0(const float* __restrict__ w, const float* __restrict__ bb,
                        const float* __restrict__ g, const float* __restrict__ bt,
                        float* __restrict__ ws) {
    int o = threadIdx.x; // 64
    float inv = 1.0f / (float)N_POS;
    float mx0 = ws[WS_XA+0]*inv, mx1 = ws[WS_XA+16]*inv, mx2 = ws[WS_XA+32]*inv;
    float C00 = ws[WS_XA+48]*inv  - mx0*mx0;
    float C01 = ws[WS_XA+64]*inv  - mx0*mx1;
    float C02 = ws[WS_XA+80]*inv  - mx0*mx2;
    float C11 = ws[WS_XA+96]*inv  - mx1*mx1;
    float C12 = ws[WS_XA+112]*inv - mx1*mx2;
    float C22 = ws[WS_XA+128]*inv - mx2*mx2;
    float w0 = w[o*3], w1 = w[o*3+1], w2 = w[o*3+2];
    float mu  = w0*mx0 + w1*mx1 + w2*mx2 + bb[o];
    float var = w0*w0*C00 + w1*w1*C11 + w2*w2*C22
              + 2.f*(w0*w1*C01 + w0*w2*C02 + w1*w2*C12);
    float sc = g[o] / sqrtf(var + 1e-5f);
    float sh = bt[o] - sc*mu;
    ws[WS_WA + o*4 + 0] = sc*w0;
    ws[WS_WA + o*4 + 1] = sc*w1;
    ws[WS_WA + o*4 + 2] = sc*w2;
    ws[WS_WA + o*4 + 3] = sc*bb[o] + sh;
}

// ---------------- z1 GEMM pass (LDS-tiled, 4pos x 8out register tiles) ----
#define ZP_BLOCKS 500
#define ZP_CHUNKS 15
template<int MODE>
__global__ __launch_bounds__(256) void k_zpass(
        const float* __restrict__ x,
        const float* __restrict__ b1g,
        const float* __restrict__ w2g,
        const float* __restrict__ b2g,
        float* __restrict__ ws) {
    __shared__ float smem[12544];         // 50176 B
    float* s_h0  = smem;                  // [64 ch][68 pos-pad]
    float* s_w1t = smem + 4352;           // [64 c][128 o]
    int tid = threadIdx.x;

    for (int i = tid; i < 8192; i += 256) s_w1t[i] = ws[WS_W1T + i];

    int pos = tid & 63, cset = tid >> 6;  // staging mapping
    int pg  = tid >> 4, og  = tid & 15;   // GEMM mapping

    float b1r[8];
    #pragma unroll
    for (int o = 0; o < 8; o++) b1r[o] = b1g[og*8 + o];
    float sc1r[8], sh1r[8], w2r[8], b2v = 0.f;
    if constexpr (MODE == 1) {
        #pragma unroll
        for (int o = 0; o < 8; o++) {
            sc1r[o] = ws[WS_SC1 + og*8 + o];
            sh1r[o] = ws[WS_SH1 + og*8 + o];
            w2r[o]  = w2g[og*8 + o];
        }
        b2v = b2g[0];
    }
    float zs[8], zq[8];
    #pragma unroll
    for (int o = 0; o < 8; o++) { zs[o] = 0.f; zq[o] = 0.f; }
    float z2s = 0.f, z2q = 0.f;

    __syncthreads();

    for (int ci = 0; ci < ZP_CHUNKS; ci++) {
        int chunk = blockIdx.x * ZP_CHUNKS + ci;
        int P = chunk*64 + pos;
        int b = P / 7500, rem = P - b*7500;
        const float* xb = x + b*22500 + rem;
        float x0 = xb[0], x1 = xb[7500], x2 = xb[15000];
        #pragma unroll
        for (int k = 0; k < 16; k++) {
            int ch = cset*16 + k;
            const float4 wa = *(const float4*)&ws[WS_WA + ch*4];
            s_h0[ch*68 + pos] = fmaxf(wa.x*x0 + wa.y*x1 + wa.z*x2 + wa.w, 0.f);
        }
        __syncthreads();

        float acc[4][8];
        #pragma unroll
        for (int p = 0; p < 4; p++)
            #pragma unroll
            for (int o = 0; o < 8; o++) acc[p][o] = 0.f;

        #pragma unroll 4
        for (int c = 0; c < 64; c++) {
            float4 ha = *(const float4*)&s_h0[c*68 + 4*pg];
            float4 wl = *(const float4*)&s_w1t[c*128 + 8*og];
            float4 wh = *(const float4*)&s_w1t[c*128 + 8*og + 4];
            #pragma unroll
            for (int p = 0; p < 4; p++) {
                float hv = ((const float*)&ha)[p];
                #pragma unroll
                for (int o = 0; o < 4; o++) {
                    acc[p][o]   = fmaf(hv, ((const float*)&wl)[o], acc[p][o]);
                    acc[p][o+4] = fmaf(hv, ((const float*)&wh)[o], acc[p][o+4]);
                }
            }
        }

        if constexpr (MODE == 0) {
            #pragma unroll
            for (int o = 0; o < 8; o++) {
                #pragma unroll
                for (int p = 0; p < 4; p++) {
                    float z = acc[p][o] + b1r[o];
                    zs[o] += z; zq[o] += z*z;
                }
            }
            __syncthreads();   // protect s_h0 before next staging
        } else {
            float zp[4];
            #pragma unroll
            for (int p = 0; p < 4; p++) {
                float s = 0.f;
                #pragma unroll
                for (int o = 0; o < 8; o++) {
                    float z = acc[p][o] + b1r[o];
                    s += w2r[o]*fmaxf(sc1r[o]*z + sh1r[o], 0.f);
                }
                zp[p] = s;
            }
            __syncthreads();               // all GEMM reads of s_h0 done
            float* s_z2p = smem;           // [64 pos][17]
            #pragma unroll
            for (int p = 0; p < 4; p++) s_z2p[(4*pg + p)*17 + og] = zp[p];
            __syncthreads();
            if (tid < 64) {
                float z2 = b2v;
                #pragma unroll
                for (int j = 0; j < 16; j++) z2 += s_z2p[tid*17 + j];
                ws[WS_Z2 + chunk*64 + tid] = z2;
                z2s += z2; z2q += z2*z2;
            }
            __syncthreads();               // protect overlay before next staging
        }
    }

    if constexpr (MODE == 0) {
        // block partials -> global arrays (NO atomics; reduced by k_z1red)
        float* s_part = smem;              // [128 o][17]
        #pragma unroll
        for (int o = 0; o < 8; o++) s_part[(og*8 + o)*17 + pg] = zs[o];
        __syncthreads();
        if (tid < 128) {
            float s = 0.f;
            #pragma unroll
            for (int j = 0; j < 16; j++) s += s_part[tid*17 + j];
            ws[WS_Z1P + blockIdx.x*128 + tid] = s;
        }
        __syncthreads();
        #pragma unroll
        for (int o = 0; o < 8; o++) s_part[(og*8 + o)*17 + pg] = zq[o];
        __syncthreads();
        if (tid < 128) {
            float s = 0.f;
            #pragma unroll
            for (int j = 0; j < 16; j++) s += s_part[tid*17 + j];
            ws[WS_Z1PQ + blockIdx.x*128 + tid] = s;
        }
    } else {
        if (tid < 64) {
            z2s = waveRed(z2s);
            z2q = waveRed(z2q);
            if (tid == 0) { atomicAdd(&ws[WS_Z2SUM], z2s); atomicAdd(&ws[WS_Z2SQ], z2q); }
        }
    }
}

// ---------------- reduce z1 partials -> BN1 affine ----------
__global__ __launch_bounds__(256) void k_z1red(const float* __restrict__ g,
                                               const float* __restrict__ bt,
                                               float* __restrict__ ws) {
    __shared__ float ss[4], qq[4];
    int o = blockIdx.x;  // 0..127
    float s = 0.f, q = 0.f;
    for (int blk = threadIdx.x; blk < ZP_BLOCKS; blk += 256) {
        s += ws[WS_Z1P  + blk*128 + o];
        q += ws[WS_Z1PQ + blk*128 + o];
    }
    s = waveRed(s); q = waveRed(q);
    int w = threadIdx.x >> 6;
    if ((threadIdx.x & 63) == 0) { ss[w] = s; qq[w] = q; }
    __syncthreads();
    if (threadIdx.x == 0) {
        float S = ss[0]+ss[1]+ss[2]+ss[3];
        float Q = qq[0]+qq[1]+qq[2]+qq[3];
        float inv = 1.0f / (float)N_POS;
        float m = S*inv;
        float v = Q*inv - m*m;
        float sc = g[o] / sqrtf(v + 1e-5f);
        ws[WS_SC1+o] = sc;
        ws[WS_SH1+o] = bt[o] - sc*m;
    }
}

__global__ void k_prep2(const float* __restrict__ g, const float* __restrict__ bt,
                        float* __restrict__ ws) {
    float inv = 1.0f / (float)N_POS;
    float m = ws[WS_Z2SUM]*inv;
    float v = ws[WS_Z2SQ]*inv - m*m;
    float sc = g[0] / sqrtf(v + 1e-5f);
    ws[WS_SC2] = sc;
    ws[WS_SH2] = bt[0] - sc*m;
}

// ---------------- x_series (b,v,t) + per-(b,v) t-mean ----------------
__global__ void k_xs(float* __restrict__ ws) {
    __shared__ float red[128];
    int bid = blockIdx.x;       // b*25+v
    int b = bid / 25, v = bid - b*25;
    float sc = ws[WS_SC2], sh = ws[WS_SH2];
    float local = 0.f;
    for (int t = threadIdx.x; t < NT; t += 128) {
        float val = fmaxf(sc * ws[WS_Z2 + b*7500 + t*25 + v] + sh, 0.f);
        ws[WS_XS + (size_t)bid*NT + t] = val;
        local += val;
    }
    red[threadIdx.x] = local;
    __syncthreads();
    for (int s = 64; s > 0; s >>= 1) {
        if (threadIdx.x < s) red[threadIdx.x] += red[threadIdx.x + s];
        __syncthreads();
    }
    if (threadIdx.x == 0) ws[WS_HM + bid] = red[0] * (1.f/300.f);
}

// ---------------- cm[b,c,i,j] = tanh(x1[b,c,i]-x2[b,c,j]) ----------------
__global__ void k_cm(const float* __restrict__ c1w, const float* __restrict__ c1b,
                     const float* __restrict__ c2w, const float* __restrict__ c2b,
                     float* __restrict__ ws) {
    __shared__ float s_hm[25];
    int bid = blockIdx.x;       // b*100+c
    int b = bid / 100, c = bid - b*100;
    if (threadIdx.x < 25) s_hm[threadIdx.x] = ws[WS_HM + b*25 + threadIdx.x];
    float a1 = c1w[c], d1 = c1b[c], a2 = c2w[c], d2 = c2b[c];
    __syncthreads();
    for (int idx = threadIdx.x; idx < 625; idx += 256) {
        int i = idx / 25, j = idx - i*25;
        ws[WS_CM + (size_t)bid*625 + idx] = tanhf(a1*s_hm[i] + d1 - a2*s_hm[j] - d2);
    }
}

// ---------------- GCs ----------------
__global__ void k_gcs(const float* __restrict__ ws, float* __restrict__ out) {
    int gid = blockIdx.x * 256 + threadIdx.x;
    if (gid < 40000) {
        int b = gid / 625; int rem = gid - b*625; int m = rem % 25;
        float acc = 0.f;
        for (int c = 0; c < 100; c++) {
            float v = ws[WS_CM + ((size_t)(b*100+c))*625 + rem];
            acc += v*v*ws[WS_SW + c*25 + m];
        }
        out[gid] = sqrtf(acc);
    }
}

// ---------------- panelty ----------------
__global__ void k_pan(float* __restrict__ ws) {
    __shared__ float s_colsq[25];
    __shared__ float s_n1, s_r;
    int tid = threadIdx.x;
    int b = blockIdx.x;
    if (tid < 25) s_colsq[tid] = 0.f;
    if (tid == 0) { s_n1 = 0.f; s_r = 0.f; }
    __syncthreads();
    float ln1 = 0.f;
    for (int idx = tid; idx < 625; idx += 256) {
        int j = idx % 25;
        float sq = 0.f;
        for (int c = 0; c < 100; c++) {
            float v = ws[WS_CM + ((size_t)(b*100+c))*625 + idx];
            sq += v*v;
        }
        ln1 += sqrtf(sq);
        atomicAdd(&s_colsq[j], sq);
    }
    ln1 = waveRed(ln1);
    if ((tid & 63) == 0) atomicAdd(&s_n1, ln1);
    __syncthreads();
    if (tid < 25) atomicAdd(&s_r, sqrtf(s_colsq[tid]));
    __syncthreads();
    if (tid == 0) atomicAdd(&ws[WS_PAN], s_n1 + s_r);
}

// ---------------- regularize ----------------
__global__ void k_reg(const float* __restrict__ f0w, const float* __restrict__ f1w,
                      const float* __restrict__ f2w, float* __restrict__ ws) {
    __shared__ float sred[4];
    int tid = blockIdx.x * blockDim.x + threadIdx.x;
    int nth = gridDim.x * blockDim.x;
    float a = 0.f;
    for (int i = tid; i < 275250; i += nth) {
        float w;
        if (i < 250000) w = f0w[i];
        else if (i < 275000) w = f1w[i - 250000];
        else w = f2w[i - 275000];
        a += w*w;
    }
    a = waveRed(a);
    int w = threadIdx.x >> 6;
    if ((threadIdx.x & 63) == 0) sred[w] = a;
    __syncthreads();
    if (threadIdx.x == 0)
        atomicAdd(&ws[WS_REG], sred[0]+sred[1]+sred[2]+sred[3]);
}

// ---------------- Fc + p per (b,c), register-tiled, t-split halves ----------
#define XP 156   // xs row pad
#define FP 152   // fc row pad
__global__ __launch_bounds__(256) void k_fcp(
        const float* __restrict__ weight, const float* __restrict__ wnorm,
        float* __restrict__ pbuf, const float* __restrict__ ws, int b_base) {
    __shared__ float s_xs[25*XP];   // 3900
    __shared__ float s_fc[25*FP];   // 3800
    __shared__ float s_wn[225];
    __shared__ float s_cm[625];
    int tid = threadIdx.x;
    int bid = blockIdx.x;
    int bl = bid / 100, c = bid - bl*100;
    int b = b_base + bl;

    for (int i = tid; i < 225; i += 256) s_wn[i] = weight[c*225 + i] / wnorm[i];
    for (int i = tid; i < 625; i += 256) s_cm[i] = ws[WS_CM + ((size_t)(b*100+c))*625 + i];

    #pragma unroll
    for (int h = 0; h < 2; h++) {
        const int t_base = h ? 148 : 0;
        const int TH     = h ? 144 : 148;
        const int NTQ4   = TH / 4;
        const int NPV    = ((TH + 7) / 8);

        for (int i = tid; i < 25*XP; i += 256) {
            int v = i / XP, u = i - v*XP;
            if (u < TH + 8) s_xs[i] = ws[WS_XS + (size_t)(b*25+v)*NT + t_base + u];
        }
        __syncthreads();

        for (int task = tid; task < 25*NTQ4; task += 256) {
            int v = task / NTQ4, tq = task - v*NTQ4;
            int t0 = tq*4;
            float4 xa = *(const float4*)&s_xs[v*XP + t0];
            float4 xb = *(const float4*)&s_xs[v*XP + t0 + 4];
            float4 xc = *(const float4*)&s_xs[v*XP + t0 + 8];
            float xr[12];
            xr[0]=xa.x; xr[1]=xa.y; xr[2]=xa.z; xr[3]=xa.w;
            xr[4]=xb.x; xr[5]=xb.y; xr[6]=xb.z; xr[7]=xb.w;
            xr[8]=xc.x; xr[9]=xc.y; xr[10]=xc.z; xr[11]=xc.w;
            float f[4];
            #pragma unroll
            for (int k = 0; k < 4; k++) f[k] = 0.f;
            #pragma unroll
            for (int l = 0; l < NTL; l++) {
                float w = s_wn[v*NTL + l];
                #pragma unroll
                for (int k = 0; k < 4; k++) f[k] = fmaf(xr[k + l], w, f[k]);
            }
            *(float4*)&s_fc[v*FP + t0] = make_float4(f[0], f[1], f[2], f[3]);
        }
        __syncthreads();

        for (int task = tid; task < NPV*25; task += 256) {
            int tq = task / 25, ii = task - tq*25;
            int t0 = tq*8;
            float cmv[25];
            #pragma unroll
            for (int v = 0; v < 25; v++) cmv[v] = s_cm[v*25 + ii];
            float acc[8];
            #pragma unroll
            for (int k = 0; k < 8; k++) acc[k] = 0.f;
            #pragma unroll
            for (int v = 0; v < 25; v++) {
                float4 f0 = *(const float4*)&s_fc[v*FP + t0];
                float4 f1 = *(const float4*)&s_fc[v*FP + t0 + 4];
                float cv = cmv[v];
                acc[0] = fmaf(cv, f0.x, acc[0]);
                acc[1] = fmaf(cv, f0.y, acc[1]);
                acc[2] = fmaf(cv, f0.z, acc[2]);
                acc[3] = fmaf(cv, f0.w, acc[3]);
                acc[4] = fmaf(cv, f1.x, acc[4]);
                acc[5] = fmaf(cv, f1.y, acc[5]);
                acc[6] = fmaf(cv, f1.z, acc[6]);
                acc[7] = fmaf(cv, f1.w, acc[7]);
            }
            size_t row = (size_t)((bl*25 + ii)*100 + c);
            size_t gbase = row*NL + t_base + t0;
            *(float4*)(pbuf + gbase) = make_float4(acc[0], acc[1], acc[2], acc[3]);
            if (t0 + 8 <= TH)
                *(float4*)(pbuf + gbase + 4) = make_float4(acc[4], acc[5], acc[6], acc[7]);
        }
        __syncthreads();
    }
}

// ---------------- group MLP: scalar-operand GEMV (R11 rewrite) -------------
// block = (bl, g, t-chunk of 64); 4 waves; wave w owns o in [25w, 25w+25);
// lane owns t. W0T/b0/w1/b1/w2/b2 via wave-uniform scalar loads; P[c][t] via
// one conflict-free ds_read_b32 per c. acc[25] statically indexed.
__global__ __launch_bounds__(256) void k_mlp(
        const float* __restrict__ pbuf, const float* __restrict__ w0t,
        const float* __restrict__ f0b,
        const float* __restrict__ f1w, const float* __restrict__ f1b,
        const float* __restrict__ f2w, const float* __restrict__ f2b,
        float* __restrict__ ws, int b_base) {
    __shared__ float sP[100*68];    // 27.2 KB; reused as s_red after GEMM
    int tid = threadIdx.x;
    int bid = blockIdx.x;
    int bl = bid / 125; int rem = bid - bl*125;
    int g = rem / 5;    int tc = rem - g*5;
    int t0 = tc*64;
    int b = b_base + bl;
    int lane = tid & 63;
    int wv = __builtin_amdgcn_readfirstlane(tid >> 6);   // wave id 0..3
    int o_base = wv*25;

    // stage sP[cc][t-64chunk]; zero-fill t >= NL
    const float* Pg = pbuf + (size_t)(bl*25 + g)*100*NL;
    for (int i = tid; i < 1600; i += 256) {
        int r = i >> 4, q = i & 15;
        int t = t0 + 4*q;
        float4 v = make_float4(0.f, 0.f, 0.f, 0.f);
        if (t + 3 < NL) {
            v = *(const float4*)(Pg + (size_t)r*NL + t);
        } else {
            float tmp0 = (t+0 < NL) ? Pg[(size_t)r*NL + t+0] : 0.f;
            float tmp1 = (t+1 < NL) ? Pg[(size_t)r*NL + t+1] : 0.f;
            float tmp2 = (t+2 < NL) ? Pg[(size_t)r*NL + t+2] : 0.f;
            float tmp3 = (t+3 < NL) ? Pg[(size_t)r*NL + t+3] : 0.f;
            v = make_float4(tmp0, tmp1, tmp2, tmp3);
        }
        *(float4*)&sP[r*68 + 4*q] = v;
    }
    __syncthreads();

    // GEMM: acc[k] = sum_c W0[o_base+k][c] * P[c][t]
    const float* w0g = w0t + g*10000;      // [c][o] contiguous in o
    float acc[25];
    #pragma unroll
    for (int k = 0; k < 25; k++) acc[k] = 0.f;
    #pragma unroll 4
    for (int c = 0; c < 100; c++) {
        float pv = sP[c*68 + lane];
        const float* wc = w0g + c*100 + o_base;   // uniform -> s_load
        #pragma unroll
        for (int k = 0; k < 25; k++)
            acc[k] = fmaf(wc[k], pv, acc[k]);
    }

    // layer 1 (scalar weights), partial acc2 over my 25 o's
    float acc2[10];
    #pragma unroll
    for (int j = 0; j < 10; j++) acc2[j] = 0.f;
    const float* b0g = f0b + g*100 + o_base;
    const float* w1g = f1w + g*1000;
    #pragma unroll
    for (int k = 0; k < 25; k++) {
        float h = fmaxf(acc[k] + b0g[k], 0.f);
        #pragma unroll
        for (int j = 0; j < 10; j++)
            acc2[j] = fmaf(w1g[j*100 + o_base + k], h, acc2[j]);
    }
    __syncthreads();               // sP GEMM reads done; reuse as s_red
    float* s_red = sP;             // [wave*10+j][68]
    #pragma unroll
    for (int j = 0; j < 10; j++) s_red[(wv*10 + j)*68 + lane] = acc2[j];
    __syncthreads();

    // layer 2 + loss on wave 0
    float local = 0.f;
    if (tid < 64) {
        int tg = t0 + lane;
        float z3 = f2b[g];
        const float* b1g = f1b + g*10;
        const float* w2g = f2w + g*10;
        #pragma unroll
        for (int j = 0; j < 10; j++) {
            float s = s_red[j*68 + lane] + s_red[(10+j)*68 + lane]
                    + s_red[(20+j)*68 + lane] + s_red[(30+j)*68 + lane];
            z3 = fmaf(w2g[j], fmaxf(s + b1g[j], 0.f), z3);
        }
        z3 = fmaxf(z3, 0.f);
        if (tg < NL-1) {
            float d = ws[WS_XS + (size_t)(b*25 + g)*NT + tg + NTL] - z3;
            local = d*d;
        }
        local = waveRed(local);
        if (tid == 0) atomicAdd(&ws[WS_Z1P + (bid & 63)*16], local);
    }
}

// ---------------- final scalars (reduce 64 loss partial lines) -------------
__global__ void k_final(float* __restrict__ out, const float* __restrict__ ws) {
    float v = ws[WS_Z1P + threadIdx.x*16];   // 64 threads
    v = waveRed(v);
    if (threadIdx.x == 0) out[40000] = v * (1.f / 465600.f);
    if (threadIdx.x == 1) out[40001] = 1e-4f * ws[WS_PAN];
    if (threadIdx.x == 2) out[40002] = 1e-4f * ws[WS_REG];
}

extern "C" void kernel_launch(void* const* d_in, const int* in_sizes, int n_in,
                              void* d_out, int out_size, void* d_ws, size_t ws_size,
                              hipStream_t stream) {
    const float* x      = (const float*)d_in[0];
    const float* weight = (const float*)d_in[1];
    const float* wnorm  = (const float*)d_in[2];
    const float* fb0_w  = (const float*)d_in[3];
    const float* fb0_b  = (const float*)d_in[4];
    const float* bn0_g  = (const float*)d_in[5];
    const float* bn0_b  = (const float*)d_in[6];
    const float* fb1_w  = (const float*)d_in[7];
    const float* fb1_b  = (const float*)d_in[8];
    const float* bn1_g  = (const float*)d_in[9];
    const float* bn1_b  = (const float*)d_in[10];
    const float* fb2_w  = (const float*)d_in[11];
    const float* fb2_b  = (const float*)d_in[12];
    const float* bn2_g  = (const float*)d_in[13];
    const float* bn2_b  = (const float*)d_in[14];
    const float* c1_w   = (const float*)d_in[15];
    const float* c1_b   = (const float*)d_in[16];
    const float* c2_w   = (const float*)d_in[17];
    const float* c2_b   = (const float*)d_in[18];
    const float* f0_w   = (const float*)d_in[19];
    const float* f0_b   = (const float*)d_in[20];
    const float* f1_w   = (const float*)d_in[21];
    const float* f1_b   = (const float*)d_in[22];
    const float* f2_w   = (const float*)d_in[23];
    const float* f2_b   = (const float*)d_in[24];

    float* ws  = (float*)d_ws;
    float* out = (float*)d_out;
    float* w0tp = ws + WS_P;           // 250000 floats
    float* pbuf = ws + WS_P + 250000;

    // zero accumulators (floats 0..255; covers XA + scalar lines)
    hipMemsetAsync(d_ws, 0, 1024, stream);

    k_xstats<<<128, 256, 0, stream>>>(x, ws);
    k_prepw<<<10, 256, 0, stream>>>(weight, ws);
    k_prepw1t<<<32, 256, 0, stream>>>(fb1_w, ws);
    k_prepw0t<<<977, 256, 0, stream>>>(f0_w, w0tp);
    k_prep0<<<1, 64, 0, stream>>>(fb0_w, fb0_b, bn0_g, bn0_b, ws);
    k_zpass<0><<<ZP_BLOCKS, 256, 0, stream>>>(x, fb1_b, fb2_w, fb2_b, ws);
    k_z1red<<<128, 256, 0, stream>>>(bn1_g, bn1_b, ws);
    // Z1P region consumed by k_z1red; re-zero 64 lines for k_mlp loss partials
    hipMemsetAsync((char*)d_ws + (size_t)WS_Z1P*4, 0, 64*16*4, stream);
    k_zpass<1><<<ZP_BLOCKS, 256, 0, stream>>>(x, fb1_b, fb2_w, fb2_b, ws);
    k_prep2<<<1, 1, 0, stream>>>(bn2_g, bn2_b, ws);
    k_xs<<<1600, 128, 0, stream>>>(ws);
    k_cm<<<6400, 256, 0, stream>>>(c1_w, c1_b, c2_w, c2_b, ws);
    k_gcs<<<157, 256, 0, stream>>>(ws, out);
    k_pan<<<64, 256, 0, stream>>>(ws);
    k_reg<<<256, 256, 0, stream>>>(f0_w, f1_w, f2_w, ws);

    // Adaptive b-chunking for the fp32 p buffer
    const size_t p_bytes_per_b = (size_t)25*100*NL*sizeof(float); // 2.92 MB
    size_t fixed_bytes = (size_t)(WS_P + 250000) * sizeof(float);
    size_t avail = ws_size > fixed_bytes ? ws_size - fixed_bytes : 0;
    int bs = (int)(avail / p_bytes_per_b);
    if (bs > 64) bs = 64;
    if (bs < 1)  bs = 1;
    for (int b0 = 0; b0 < 64; b0 += bs) {
        int nb = (64 - b0) < bs ? (64 - b0) : bs;
        k_fcp<<<nb*100, 256, 0, stream>>>(weight, wnorm, pbuf, ws, b0);
        k_mlp<<<nb*125, 256, 0, stream>>>(pbuf, w0tp, f0_b, f1_w, f1_b,
                                          f2_w, f2_b, ws, b0);
    }
    k_final<<<1, 64, 0, stream>>>(out, ws);
}